// Round 11
// baseline (98.083 us; speedup 1.0000x reference)
//
#include <hip/hip_runtime.h>

#define N2 128
#define MM 16384
#define START 6
#define CB 32        // columns per block -> 512 blocks -> 2 blocks/CU
#define BT 256       // 4 waves; 8 shares of 32 lanes; share g owns row-groups {g, 15-g}
#define FSTR 143     // fC stride (odd => conflict-free col-major); idx = 15 + d

__global__ __launch_bounds__(BT, 2) void npi_fused(
    const float* __restrict__ rt, const float* __restrict__ dgt,
    const float* __restrict__ si, const float* __restrict__ f,
    const float* __restrict__ seed, float* __restrict__ out)
{
    __shared__ float fC[CB * FSTR];             // 17.9 KiB [c][15+d], zero for d<2
    __shared__ float hbuf[2 * 16 * CB];         //  4.0 KiB double-buffered H publish
    __shared__ __align__(16) float sa[128];     // sa[x] = si[x+1] (aligned windows)
    __shared__ float lred[4];

    const int t = threadIdx.x;
    const int c = t & 31;
    const int g = t >> 5;          // share 0..7
    const int w = t >> 6;
    const int m = blockIdx.x * CB + c;

    // ---- global loads (fired early; latency hidden under staging) ----
    float fregs[16];
#pragma unroll
    for (int q = 0; q < 16; ++q)
        fregs[q] = f[((g << 4) + q) * MM + m];
    float sd[START];
#pragma unroll
    for (int k = 0; k < START; ++k) sd[k] = seed[k * MM + m];
    float rtv[16];
#pragma unroll
    for (int k = 0; k < 16; ++k) rtv[k] = rt[k * MM + m];
    float dgv[2][8];
#pragma unroll
    for (int pass = 0; pass < 2; ++pass) {
        const int gi = pass ? (15 - g) : g;
#pragma unroll
        for (int r = 0; r < 8; ++r)
            dgv[pass][r] = dgt[((gi << 3) + r) * MM + m];
    }

    // ---- stage sa + fC ----
    if (t < 128) sa[t] = (t < 127) ? si[t + 1] : 0.f;
#pragma unroll
    for (int z = 0; z < 2; ++z) {
        int p = t + z * BT;
        if (p < 15 * CB) fC[(p & 31) * FSTR + (p >> 5)] = 0.f;  // idx 0..14 (d<0)
    }
#pragma unroll
    for (int q = 0; q < 16; ++q) {
        int d = (g << 4) + q;
        fC[c * FSTR + 15 + d] = (d < 2) ? 0.f : fregs[q];
    }

    // sr[1..15] via scalar loads (uniform constant index -> s_load, no LDS)
    float sr[16];
#pragma unroll
    for (int k = 1; k < 16; ++k) sr[k] = si[k];

    __syncthreads();

    float Hacc[2][8], Eacc[2][8];
#pragma unroll
    for (int pass = 0; pass < 2; ++pass)
#pragma unroll
        for (int r = 0; r < 8; ++r) { Hacc[pass][r] = 0.f; Eacc[pass][r] = 0.f; }

    float v[16], rtn[16];

    // ================= chunk 0 =================
    {
        float p_[16];
#pragma unroll
        for (int k = 0; k < 16; ++k) p_[k] = 0.f;
#pragma unroll
        for (int k = 0; k < 16; ++k) {
            float vk;
            if (k < START) vk = sd[k];
            else vk = rtv[k] * (p_[k] + sr[1] * v[k - 1]);
            v[k] = vk;
#pragma unroll
            for (int k2 = k + 2; k2 < 16; ++k2)
                p_[k2] += sr[k2 - k] * vk;
        }
    }
#pragma unroll
    for (int k = 0; k < 16; ++k) rtn[k] = rt[(16 + k) * MM + m];  // prefetch
#pragma unroll
    for (int pass = 0; pass < 2; ++pass) {
        const int gi = pass ? (15 - g) : g;
        if (gi >= 2) {                         // H: strictly future rows
            const int base = (gi << 3) - 16;   // = off-1, multiple of 8
            float sw[24];
            const float4* sap = (const float4*)(sa + base);
#pragma unroll
            for (int e4 = 0; e4 < 6; ++e4) {
                float4 q4 = sap[e4];
                sw[4 * e4 + 0] = q4.x; sw[4 * e4 + 1] = q4.y;
                sw[4 * e4 + 2] = q4.z; sw[4 * e4 + 3] = q4.w;
            }
            // sw[e] == si[off + e], off = 8gi - 15
#pragma unroll
            for (int r = 0; r < 8; ++r)
#pragma unroll
                for (int k = 0; k < 16; ++k)
                    Hacc[pass][r] += v[k] * sw[15 + r - k];
        }
        {                                      // E: zero-pad handles d<2
            const int offE = (gi << 3);
            float fw[23];
#pragma unroll
            for (int e = 0; e < 23; ++e) fw[e] = fC[c * FSTR + offE + e];
#pragma unroll
            for (int r = 0; r < 8; ++r)
#pragma unroll
                for (int k = 0; k < 16; ++k)
                    Eacc[pass][r] += v[k] * fw[15 + r - k];
        }
    }
#pragma unroll
    for (int k = 0; k < 16; ++k) rtv[k] = rtn[k];

    // ================= chunks 1..7 (ONE barrier per chunk) =================
    for (int cb = 1; cb < 8; ++cb) {
        float* hb = hbuf + ((cb & 1) << 9);
        // owners publish this chunk's H (complete through chunk cb-1)
#pragma unroll
        for (int pass = 0; pass < 2; ++pass) {
            const int gi = pass ? (15 - g) : g;
            if ((gi >> 1) == cb) {
#pragma unroll
                for (int r = 0; r < 8; ++r)
                    hb[((((gi & 1) << 3) + r) << 5) + c] = Hacc[pass][r];
            }
        }
        __syncthreads();

        // triangle (redundant per lane; short dependence chain)
        float p_[16];
#pragma unroll
        for (int k = 0; k < 16; ++k) p_[k] = hb[(k << 5) + c];
#pragma unroll
        for (int k = 0; k < 16; ++k) {
            float vk = (k == 0) ? (rtv[0] * p_[0])
                                : (rtv[k] * (p_[k] + sr[1] * v[k - 1]));
            v[k] = vk;
#pragma unroll
            for (int k2 = k + 2; k2 < 16; ++k2)
                p_[k2] += sr[k2 - k] * vk;
        }
        if (cb < 7) {
#pragma unroll
            for (int k = 0; k < 16; ++k)
                rtn[k] = rt[(((cb + 1) << 4) + k) * MM + m];
        }

        // accumulate this chunk's H/E contributions into owned rows
#pragma unroll
        for (int pass = 0; pass < 2; ++pass) {
            const int gi = pass ? (15 - g) : g;
            if (gi >= 2 * cb + 2) {
                const int base = (gi << 3) - (cb << 4) - 16;   // >= 0, mult of 8
                float sw[24];
                const float4* sap = (const float4*)(sa + base);
#pragma unroll
                for (int e4 = 0; e4 < 6; ++e4) {
                    float4 q4 = sap[e4];
                    sw[4 * e4 + 0] = q4.x; sw[4 * e4 + 1] = q4.y;
                    sw[4 * e4 + 2] = q4.z; sw[4 * e4 + 3] = q4.w;
                }
#pragma unroll
                for (int r = 0; r < 8; ++r)
#pragma unroll
                    for (int k = 0; k < 16; ++k)
                        Hacc[pass][r] += v[k] * sw[15 + r - k];
            }
            if (gi >= 2 * cb) {
                const int offE = (gi << 3) - (cb << 4);        // >= 0
                float fw[23];
#pragma unroll
                for (int e = 0; e < 23; ++e) fw[e] = fC[c * FSTR + offE + e];
#pragma unroll
                for (int r = 0; r < 8; ++r)
#pragma unroll
                    for (int k = 0; k < 16; ++k)
                        Eacc[pass][r] += v[k] * fw[15 + r - k];
            }
        }
#pragma unroll
        for (int k = 0; k < 16; ++k) rtv[k] = rtn[k];
    }

    // ---- loss ----
    float lsum = 0.f;
#pragma unroll
    for (int pass = 0; pass < 2; ++pass) {
        const int gi = pass ? (15 - g) : g;
#pragma unroll
        for (int r = 0; r < 8; ++r) {
            const int i = (gi << 3) + r;
            float e = Eacc[pass][r];
            if (i == 0) e = 1e-9f;
            else if (i < START) e = 0.f;
            float diff = e - dgv[pass][r];
            lsum += diff * diff;
        }
    }
#pragma unroll
    for (int off = 32; off > 0; off >>= 1)
        lsum += __shfl_down(lsum, off, 64);
    if ((t & 63) == 0) lred[w] = lsum;
    __syncthreads();
    if (t == 0)
        atomicAdd(out, (lred[0] + lred[1] + lred[2] + lred[3]) *
                       (1.0f / ((float)N2 * (float)MM)));
}

extern "C" void kernel_launch(void* const* d_in, const int* in_sizes, int n_in,
                              void* d_out, int out_size, void* d_ws, size_t ws_size,
                              hipStream_t stream) {
    const float* rt   = (const float*)d_in[0];
    const float* dgt  = (const float*)d_in[1];
    const float* si   = (const float*)d_in[2];
    const float* f    = (const float*)d_in[3];
    const float* seed = (const float*)d_in[4];

    hipMemsetAsync(d_out, 0, sizeof(float), stream);
    npi_fused<<<dim3(MM / CB), dim3(BT), 0, stream>>>(
        rt, dgt, si, f, seed, (float*)d_out);
}